// Round 8
// baseline (1712.362 us; speedup 1.0000x reference)
//
#include <hip/hip_runtime.h>
#include <hip/hip_bf16.h>
#include <cstdint>

// Instance: B=4,S=4096 -> T=16384, D=1024, E=8, H=1024, top_k=2. f32 in/out.
#define T_TOK 16384
#define DDIM  1024

typedef __attribute__((ext_vector_type(8))) short bf16x8;
typedef __attribute__((ext_vector_type(4))) float f32x4;

__device__ __forceinline__ unsigned short f2bf(float f) {
  unsigned u = __builtin_bit_cast(unsigned, f);
  return (unsigned short)((u + 0x7fffu + ((u >> 16) & 1u)) >> 16);  // RNE
}
__device__ __forceinline__ unsigned pk2(float a, float b) {
  return (unsigned)f2bf(a) | ((unsigned)f2bf(b) << 16);
}
__device__ __forceinline__ void gload16(const void* g, void* l) {
  typedef __attribute__((address_space(1))) const unsigned int gu32;
  typedef __attribute__((address_space(3))) unsigned int lu32;
  __builtin_amdgcn_global_load_lds((gu32*)g, (lu32*)l, 16, 0, 0);
}

// ---------------------------------------------------------------------------
// Transpose-convert weights f32->bf16 (unchanged, verified).
// ---------------------------------------------------------------------------
__global__ __launch_bounds__(256) void convert_k(
    const float* __restrict__ gw, const float* __restrict__ pw,
    const float* __restrict__ ow, char* __restrict__ wg,
    char* __restrict__ wp, char* __restrict__ wo) {
  __shared__ float t[64][65];
  const int z = blockIdx.z;
  const int arr = z >> 3, e = z & 7;
  const float* src = (arr == 0 ? gw : arr == 1 ? pw : ow) + ((long)e << 20);
  char* dst = (arr == 0 ? wg : arr == 1 ? wp : wo) + ((long)e << 21);
  const int r0 = blockIdx.x * 64, c0 = blockIdx.y * 64;
  const int row = threadIdx.x >> 2, q = threadIdx.x & 3;
  const float4* sp = (const float4*)(src + (long)(r0 + row) * 1024 + c0 + q * 16);
  float4 v0 = sp[0], v1 = sp[1], v2 = sp[2], v3 = sp[3];
  float* tr = &t[row][q * 16];
  tr[0]=v0.x; tr[1]=v0.y; tr[2]=v0.z; tr[3]=v0.w;
  tr[4]=v1.x; tr[5]=v1.y; tr[6]=v1.z; tr[7]=v1.w;
  tr[8]=v2.x; tr[9]=v2.y; tr[10]=v2.z; tr[11]=v2.w;
  tr[12]=v3.x; tr[13]=v3.y; tr[14]=v3.z; tr[15]=v3.w;
  __syncthreads();
  const int cl = row, rq = q;
  uint4 o0, o1;
  o0.x = pk2(t[rq*16+ 0][cl], t[rq*16+ 1][cl]);
  o0.y = pk2(t[rq*16+ 2][cl], t[rq*16+ 3][cl]);
  o0.z = pk2(t[rq*16+ 4][cl], t[rq*16+ 5][cl]);
  o0.w = pk2(t[rq*16+ 6][cl], t[rq*16+ 7][cl]);
  o1.x = pk2(t[rq*16+ 8][cl], t[rq*16+ 9][cl]);
  o1.y = pk2(t[rq*16+10][cl], t[rq*16+11][cl]);
  o1.z = pk2(t[rq*16+12][cl], t[rq*16+13][cl]);
  o1.w = pk2(t[rq*16+14][cl], t[rq*16+15][cl]);
  char* dp = dst + (long)(c0 + cl) * 2048 + (long)(r0 + rq * 16) * 2;
  *(uint4*)dp = o0;
  *(uint4*)(dp + 16) = o1;
}

// ---------------------------------------------------------------------------
// Router (unchanged, verified).
// ---------------------------------------------------------------------------
__global__ __launch_bounds__(256) void router_k(
    const float* __restrict__ x, const float* __restrict__ gatew,
    float* __restrict__ logitsOut, float4* __restrict__ route,
    float* __restrict__ accum, unsigned short* __restrict__ xbo) {
  __shared__ float accB[16];
  const int tid = threadIdx.x;
  if (tid < 16) accB[tid] = 0.f;
  __syncthreads();
  const int lane = tid & 63;
  const int gwave = blockIdx.x * 4 + (tid >> 6);

  for (int g = gwave; g < 4096; g += 1024) {
    const int t0 = g * 4;
    float s[4][8];
#pragma unroll
    for (int tt = 0; tt < 4; ++tt)
#pragma unroll
      for (int e = 0; e < 8; ++e) s[tt][e] = 0.f;

    for (int i = 0; i < 16; ++i) {
      int d = lane + i * 64;
      float4 w0 = *(const float4*)(gatew + d * 8);
      float4 w1 = *(const float4*)(gatew + d * 8 + 4);
#pragma unroll
      for (int tt = 0; tt < 4; ++tt) {
        float xv = x[(long)(t0 + tt) * DDIM + d];
        if (xbo) xbo[(long)(t0 + tt) * DDIM + d] = f2bf(xv);
        s[tt][0] += xv * w0.x; s[tt][1] += xv * w0.y;
        s[tt][2] += xv * w0.z; s[tt][3] += xv * w0.w;
        s[tt][4] += xv * w1.x; s[tt][5] += xv * w1.y;
        s[tt][6] += xv * w1.z; s[tt][7] += xv * w1.w;
      }
    }
#pragma unroll
    for (int m = 1; m < 64; m <<= 1)
#pragma unroll
      for (int tt = 0; tt < 4; ++tt)
#pragma unroll
        for (int e = 0; e < 8; ++e) s[tt][e] += __shfl_xor(s[tt][e], m);

    float psum[8];
#pragma unroll
    for (int e = 0; e < 8; ++e) psum[e] = 0.f;
    int i1a[4], i2a[4];
    float w1a[4], w2a[4];
#pragma unroll
    for (int tt = 0; tt < 4; ++tt) {
      float mx = s[tt][0];
#pragma unroll
      for (int e = 1; e < 8; ++e) mx = fmaxf(mx, s[tt][e]);
      float pe[8], Z = 0.f;
#pragma unroll
      for (int e = 0; e < 8; ++e) { pe[e] = __expf(s[tt][e] - mx); Z += pe[e]; }
      float inv = 1.f / Z;
#pragma unroll
      for (int e = 0; e < 8; ++e) { pe[e] *= inv; psum[e] += pe[e]; }
      int i1 = 0; float p1 = pe[0];
#pragma unroll
      for (int e = 1; e < 8; ++e) if (pe[e] > p1) { p1 = pe[e]; i1 = e; }
      int i2 = -1; float p2 = -1.f;
#pragma unroll
      for (int e = 0; e < 8; ++e)
        if (e != i1 && pe[e] > p2) { p2 = pe[e]; i2 = e; }
      float wsum = p1 + p2;
      i1a[tt] = i1; i2a[tt] = i2;
      w1a[tt] = p1 / wsum; w2a[tt] = p2 / wsum;
    }
    if (lane < 32) {
      int tt = lane >> 3, e = lane & 7;
      logitsOut[(t0 + tt) * 8 + e] = s[tt][e];
    }
    if (lane < 32 && (lane & 7) == 0) {
      int tt = lane >> 3;
      float4 rr;
      rr.x = w1a[tt]; rr.y = w2a[tt];
      rr.z = __int_as_float(i1a[tt]); rr.w = __int_as_float(i2a[tt]);
      route[t0 + tt] = rr;
    }
    if (lane < 8) {
      float c = 0.f;
#pragma unroll
      for (int tt = 0; tt < 4; ++tt)
        c += (float)(i1a[tt] == lane) + (float)(i2a[tt] == lane);
      atomicAdd(&accB[lane], psum[lane]);
      atomicAdd(&accB[8 + lane], c);
    }
  }
  __syncthreads();
  if (tid < 16) atomicAdd(&accum[tid], accB[tid]);
}

// ---------------------------------------------------------------------------
// offsets_k: per-expert slot offsets + cumulative 256-slot tile counts.
// ---------------------------------------------------------------------------
__global__ void offsets_k(const float* __restrict__ accum,
                          int* __restrict__ offs, int* __restrict__ cursor,
                          int* __restrict__ cumT) {
  if (threadIdx.x == 0) {
    int c = 0;
#pragma unroll
    for (int e = 0; e < 8; ++e) {
      offs[e] = c; cursor[e] = c;
      c += (int)(accum[8 + e] + 0.5f);
    }
    offs[8] = c;
    int t = 0;
#pragma unroll
    for (int e = 0; e < 8; ++e) {
      cumT[e] = t;
      t += (offs[e + 1] - offs[e] + 255) >> 8;
    }
    cumT[8] = t;
  }
}

__global__ __launch_bounds__(256) void scatter_k(
    const float4* __restrict__ route, int* __restrict__ cursor,
    int* __restrict__ list, float* __restrict__ wsl) {
  int t = blockIdx.x * 256 + threadIdx.x;
  float4 rr = route[t];
  int i1 = __float_as_int(rr.z), i2 = __float_as_int(rr.w);
  int s1 = atomicAdd(&cursor[i1], 1);
  list[s1] = t; wsl[s1] = rr.x;
  int s2 = atomicAdd(&cursor[i2], 1);
  list[s2] = t; wsl[s2] = rr.y;
}

// ---------------------------------------------------------------------------
// Pass 1 grouped GEMM. Tile 256 slots x 128 h-cols (dual g/p). SINGLE-buffer
// LDS (64 KiB) + __launch_bounds__(512,4) -> 2 blocks/CU co-resident: the
// other block's MFMA covers this block's stage/barrier stall (m114 overlap).
// Dense grid: blockIdx.x -> (e,tile) via cumT. 2-barrier verified skeleton.
// ---------------------------------------------------------------------------
template <int XB>
__global__ __launch_bounds__(512, 4) void pass1_k(
    const float* __restrict__ x, const unsigned short* __restrict__ xb,
    const char* __restrict__ wg, const char* __restrict__ wp,
    const int* __restrict__ list, const float* __restrict__ wsl,
    const int* __restrict__ offs, const int* __restrict__ cumT,
    char* __restrict__ hw) {
  __shared__ __align__(16) char Al[32768];
  __shared__ __align__(16) char Bgl[16384];
  __shared__ __align__(16) char Bpl[16384];
  const int b = blockIdx.x;
  if (b >= cumT[8]) return;
  int e = 0;
#pragma unroll
  for (int i = 1; i < 8; ++i) e += (b >= cumT[i]);
  const int tile = b - cumT[e];
  const int start = offs[e] + tile * 256;
  const int valid = min(256, offs[e + 1] - start);
  const int chunk = blockIdx.y;  // h-cols chunk*128
  const int tid = threadIdx.x, lane = tid & 63, wid = tid >> 6;

  const int l8 = lane >> 3, seg = lane & 7;
  const unsigned inrow = ((unsigned)(seg * 16)) ^ (((unsigned)l8) << 4);

  // A staging: 4 insts/wave, rows wid*32 + i*8 + l8 (gathered tokens)
  const char* asrc[4];
  unsigned adst[4];
#pragma unroll
  for (int i = 0; i < 4; ++i) {
    int row = wid * 32 + i * 8 + l8;
    int tok = list[start + min(row, valid - 1)];
    asrc[i] = (const char*)xb + ((long)tok << 11) + inrow;
    adst[i] = (unsigned)(wid * 4096 + i * 1024);
  }
  // B staging: 2+2 insts/wave, h-rows wid*16 + i*8 + l8
  const long wbase = ((long)e << 21) + ((long)(chunk * 128) << 11);
  const char* gsrc[2];
  const char* psrc[2];
  unsigned bdst[2];
#pragma unroll
  for (int i = 0; i < 2; ++i) {
    int h = wid * 16 + i * 8 + l8;
    gsrc[i] = wg + wbase + ((long)h << 11) + inrow;
    psrc[i] = wp + wbase + ((long)h << 11) + inrow;
    bdst[i] = (unsigned)(wid * 2048 + i * 1024);
  }

  f32x4 aG[8][2], aP[8][2];
#pragma unroll
  for (int f = 0; f < 8; ++f)
#pragma unroll
    for (int j = 0; j < 2; ++j) {
      aG[f][j] = (f32x4){0.f, 0.f, 0.f, 0.f};
      aP[f][j] = (f32x4){0.f, 0.f, 0.f, 0.f};
    }

  const int col = lane & 15, kg = lane >> 4;
  const int mb = (wid >> 2) * 128, nb = (wid & 3) * 32;

#define P1_STAGE(kb)                                          \
  {                                                           \
    long ko = (long)(kb) << 7;                                \
    gload16(asrc[0] + ko, Al + adst[0]);                      \
    gload16(asrc[1] + ko, Al + adst[1]);                      \
    gload16(asrc[2] + ko, Al + adst[2]);                      \
    gload16(asrc[3] + ko, Al + adst[3]);                      \
    gload16(gsrc[0] + ko, Bgl + bdst[0]);                     \
    gload16(gsrc[1] + ko, Bgl + bdst[1]);                     \
    gload16(psrc[0] + ko, Bpl + bdst[0]);                     \
    gload16(psrc[1] + ko, Bpl + bdst[1]);                     \
  }
#define P1_COMPUTE()                                                        \
  _Pragma("unroll") for (int ks = 0; ks < 2; ++ks) {                        \
    bf16x8 bg[2], bp[2];                                                    \
    _Pragma("unroll") for (int j = 0; j < 2; ++j) {                         \
      int n = nb + j * 16 + col;                                            \
      unsigned off = (unsigned)(n * 128 + ks * 64 + kg * 16) ^              \
                     (((unsigned)n & 7u) << 4);                             \
      bg[j] = *(const bf16x8*)(Bgl + off);                                  \
      bp[j] = *(const bf16x8*)(Bpl + off);                                  \
    }                                                                       \
    _Pragma("unroll") for (int f = 0; f < 8; ++f) {                         \
      int r = mb + f * 16 + col;                                            \
      bf16x8 a = *(const bf16x8*)(                                          \
          Al + ((unsigned)(r * 128 + ks * 64 + kg * 16) ^                   \
                (((unsigned)r & 7u) << 4)));                                \
      _Pragma("unroll") for (int j = 0; j < 2; ++j) {                       \
        aG[f][j] = __builtin_amdgcn_mfma_f32_16x16x32_bf16(a, bg[j],        \
                                                           aG[f][j], 0, 0, 0); \
        aP[f][j] = __builtin_amdgcn_mfma_f32_16x16x32_bf16(a, bp[j],        \
                                                           aP[f][j], 0, 0, 0); \
      }                                                                     \
    }                                                                       \
  }

  if (XB) {
#pragma unroll 1
    for (int kb = 0; kb < 16; ++kb) {
      __syncthreads();  // all waves done reading buf (prev iter)
      P1_STAGE(kb);
      __syncthreads();  // stage landed (implicit vmcnt(0) drain)
      P1_COMPUTE();
    }
  } else {
    // Fallback (ws too small for xb): reg-staged f32 A + gload_lds B.
    const int sr2 = tid >> 1, q2 = tid & 1;
    const int tokS = list[start + min(sr2, valid - 1)];
    const float* axp = x + (long)tokS * DDIM + q2 * 32;
    const unsigned swzS = ((unsigned)(sr2 & 7)) << 4;
    const unsigned sbS = (unsigned)(sr2 * 128 + q2 * 64);
#pragma unroll 1
    for (int kb = 0; kb < 16; ++kb) {
      __syncthreads();
      {
        const float4* ap = (const float4*)(axp + kb * 64);
#pragma unroll
        for (int m = 0; m < 4; ++m) {
          float4 v0 = ap[m * 2], v1 = ap[m * 2 + 1];
          uint4 w;
          w.x = pk2(v0.x, v0.y); w.y = pk2(v0.z, v0.w);
          w.z = pk2(v1.x, v1.y); w.w = pk2(v1.z, v1.w);
          *(uint4*)(Al + ((sbS + m * 16) ^ swzS)) = w;
        }
        long ko = (long)kb << 7;
        gload16(gsrc[0] + ko, Bgl + bdst[0]);
        gload16(gsrc[1] + ko, Bgl + bdst[1]);
        gload16(psrc[0] + ko, Bpl + bdst[0]);
        gload16(psrc[1] + ko, Bpl + bdst[1]);
      }
      __syncthreads();
      P1_COMPUTE();
    }
  }

  const int rg = lane >> 4;
#pragma unroll
  for (int f = 0; f < 8; ++f) {
#pragma unroll
    for (int r = 0; r < 4; ++r) {
      int ml = mb + f * 16 + rg * 4 + r;
      if (ml < valid) {
        int slot = start + ml;
        float wv = wsl[slot];
#pragma unroll
        for (int j = 0; j < 2; ++j) {
          float g = aG[f][j][r], p = aP[f][j][r];
          float h = g * (p / (1.f + __expf(-p))) * wv;
          int hc = chunk * 128 + nb + j * 16 + col;
          *(unsigned short*)(hw + (((long)slot << 11) + (hc << 1))) = f2bf(h);
        }
      }
    }
  }
}

// ---------------------------------------------------------------------------
// Pass 2 grouped GEMM. Tile 256 slots x 128 d-cols. Single-buffer 48 KiB,
// (512,4) -> 2 blocks/CU. Dense grid via cumT. atomicAdd epilogue.
// ---------------------------------------------------------------------------
__global__ __launch_bounds__(512, 4) void pass2_k(
    const char* __restrict__ hw, const char* __restrict__ wo,
    const int* __restrict__ list, const int* __restrict__ offs,
    const int* __restrict__ cumT, float* __restrict__ out) {
  __shared__ __align__(16) char Al[32768];
  __shared__ __align__(16) char Bl[16384];
  const int b = blockIdx.x;
  if (b >= cumT[8]) return;
  int e = 0;
#pragma unroll
  for (int i = 1; i < 8; ++i) e += (b >= cumT[i]);
  const int tile = b - cumT[e];
  const int start = offs[e] + tile * 256;
  const int valid = min(256, offs[e + 1] - start);
  const int chunk = blockIdx.y;  // d-cols chunk*128
  const int tid = threadIdx.x, lane = tid & 63, wid = tid >> 6;

  const int l8 = lane >> 3, seg = lane & 7;
  const unsigned inrow = ((unsigned)(seg * 16)) ^ (((unsigned)l8) << 4);

  const char* asrc[4];
  unsigned adst[4];
#pragma unroll
  for (int i = 0; i < 4; ++i) {
    int row = wid * 32 + i * 8 + l8;
    asrc[i] = hw + ((long)(start + min(row, valid - 1)) << 11) + inrow;
    adst[i] = (unsigned)(wid * 4096 + i * 1024);
  }
  const char* bsrc[2];
  unsigned bdst[2];
#pragma unroll
  for (int i = 0; i < 2; ++i) {
    int n = wid * 16 + i * 8 + l8;
    bsrc[i] = wo + ((long)e << 21) + ((long)(chunk * 128 + n) << 11) + inrow;
    bdst[i] = (unsigned)(wid * 2048 + i * 1024);
  }

  f32x4 acc[8][2];
#pragma unroll
  for (int f = 0; f < 8; ++f)
#pragma unroll
    for (int j = 0; j < 2; ++j) acc[f][j] = (f32x4){0.f, 0.f, 0.f, 0.f};

  const int col = lane & 15, kg = lane >> 4;
  const int mb = (wid >> 2) * 128, nb = (wid & 3) * 32;

#pragma unroll 1
  for (int kb = 0; kb < 16; ++kb) {
    __syncthreads();
    {
      long ko = (long)kb << 7;
      gload16(asrc[0] + ko, Al + adst[0]);
      gload16(asrc[1] + ko, Al + adst[1]);
      gload16(asrc[2] + ko, Al + adst[2]);
      gload16(asrc[3] + ko, Al + adst[3]);
      gload16(bsrc[0] + ko, Bl + bdst[0]);
      gload16(bsrc[1] + ko, Bl + bdst[1]);
    }
    __syncthreads();
#pragma unroll
    for (int ks = 0; ks < 2; ++ks) {
      bf16x8 bf2[2];
#pragma unroll
      for (int j = 0; j < 2; ++j) {
        int n = nb + j * 16 + col;
        bf2[j] = *(const bf16x8*)(
            Bl + ((unsigned)(n * 128 + ks * 64 + kg * 16) ^
                  (((unsigned)n & 7u) << 4)));
      }
#pragma unroll
      for (int f = 0; f < 8; ++f) {
        int r = mb + f * 16 + col;
        bf16x8 a = *(const bf16x8*)(
            Al + ((unsigned)(r * 128 + ks * 64 + kg * 16) ^
                  (((unsigned)r & 7u) << 4)));
#pragma unroll
        for (int j = 0; j < 2; ++j)
          acc[f][j] = __builtin_amdgcn_mfma_f32_16x16x32_bf16(a, bf2[j],
                                                              acc[f][j], 0, 0, 0);
      }
    }
  }

  const int rg = lane >> 4;
#pragma unroll
  for (int f = 0; f < 8; ++f) {
#pragma unroll
    for (int r = 0; r < 4; ++r) {
      int ml = mb + f * 16 + rg * 4 + r;
      if (ml < valid) {
        int token = list[start + ml];
#pragma unroll
        for (int j = 0; j < 2; ++j) {
          int c = chunk * 128 + nb + j * 16 + col;
          atomicAdd(&out[(long)token * DDIM + c], acc[f][j][r]);
        }
      }
    }
  }
}

// ---------------------------------------------------------------------------
__global__ void loss_k(const float* __restrict__ accum, float* __restrict__ out) {
  if (threadIdx.x == 0 && blockIdx.x == 0) {
    float L = 0.f;
#pragma unroll
    for (int e = 0; e < 8; ++e) L += accum[e] * accum[8 + e];
    out[0] = L * 8.f / ((float)T_TOK * (float)T_TOK);
  }
}

// ---------------------------------------------------------------------------
extern "C" void kernel_launch(void* const* d_in, const int* in_sizes, int n_in,
                              void* d_out, int out_size, void* d_ws,
                              size_t ws_size, hipStream_t stream) {
  const float* x     = (const float*)d_in[0];
  const float* gatew = (const float*)d_in[1];
  const float* gw    = (const float*)d_in[2];
  const float* pw    = (const float*)d_in[3];
  const float* ow    = (const float*)d_in[4];

  float* out       = (float*)d_out;
  float* logitsOut = out + (long)T_TOK * DDIM;
  float* lossOut   = out + (long)T_TOK * DDIM + T_TOK * 8;

  char* wsB = (char*)d_ws;
  float*  accum  = (float*)wsB;
  int*    cursor = (int*)(wsB + 64);
  int*    offs   = (int*)(wsB + 96);
  int*    cumT   = (int*)(wsB + 160);
  float4* route  = (float4*)(wsB + 1024);
  int*    list   = (int*)(wsB + 263168);
  float*  wsl    = (float*)(wsB + 394240);
  char*   wg     = wsB + (1l << 20);
  char*   wp     = wsB + 17825792;
  char*   wo     = wsB + 34603008;
  char*   hw     = wsB + 51380224;                          // 64 MiB
  unsigned short* xb = (unsigned short*)(wsB + 118489088);  // 32 MiB
  const bool big = ws_size >= 152043520ul;

  hipMemsetAsync(d_out, 0, (size_t)out_size * 4, stream);
  hipMemsetAsync(accum, 0, 64, stream);
  convert_k<<<dim3(16, 16, 24), 256, 0, stream>>>(gw, pw, ow, wg, wp, wo);
  router_k<<<256, 256, 0, stream>>>(x, gatew, logitsOut, route, accum,
                                    big ? xb : nullptr);
  offsets_k<<<1, 64, 0, stream>>>(accum, offs, cursor, cumT);
  scatter_k<<<64, 256, 0, stream>>>(route, cursor, list, wsl);
  if (big)
    pass1_k<1><<<dim3(136, 8), 512, 0, stream>>>(x, xb, wg, wp, list, wsl,
                                                 offs, cumT, hw);
  else
    pass1_k<0><<<dim3(136, 8), 512, 0, stream>>>(x, xb, wg, wp, list, wsl,
                                                 offs, cumT, hw);
  pass2_k<<<dim3(136, 8), 512, 0, stream>>>(hw, wo, list, offs, cumT, out);
  loss_k<<<1, 64, 0, stream>>>(accum, lossOut);
}

// Round 9
// 732.612 us; speedup vs baseline: 2.3373x; 2.3373x over previous
//
#include <hip/hip_runtime.h>
#include <hip/hip_bf16.h>
#include <cstdint>

// Instance: B=4,S=4096 -> T=16384, D=1024, E=8, H=1024, top_k=2. f32 in/out.
#define T_TOK 16384
#define DDIM  1024

typedef __attribute__((ext_vector_type(8))) short bf16x8;
typedef __attribute__((ext_vector_type(4))) float f32x4;

__device__ __forceinline__ unsigned short f2bf(float f) {
  unsigned u = __builtin_bit_cast(unsigned, f);
  return (unsigned short)((u + 0x7fffu + ((u >> 16) & 1u)) >> 16);  // RNE
}
__device__ __forceinline__ unsigned pk2(float a, float b) {
  return (unsigned)f2bf(a) | ((unsigned)f2bf(b) << 16);
}
__device__ __forceinline__ void gload16(const void* g, void* l) {
  typedef __attribute__((address_space(1))) const unsigned int gu32;
  typedef __attribute__((address_space(3))) unsigned int lu32;
  __builtin_amdgcn_global_load_lds((gu32*)g, (lu32*)l, 16, 0, 0);
}

#define SBAR()                        \
  __builtin_amdgcn_sched_barrier(0);  \
  __builtin_amdgcn_s_barrier();       \
  __builtin_amdgcn_sched_barrier(0)
#define WAIT_VM8()                                        \
  asm volatile("s_waitcnt vmcnt(8)" ::: "memory");        \
  __builtin_amdgcn_sched_barrier(0)
#define WAIT_VM0()                                        \
  asm volatile("s_waitcnt vmcnt(0)" ::: "memory");        \
  __builtin_amdgcn_sched_barrier(0)
#define WAIT_LGKM0()                                      \
  asm volatile("s_waitcnt lgkmcnt(0)" ::: "memory");      \
  __builtin_amdgcn_sched_barrier(0)

// ---------------------------------------------------------------------------
// Transpose-convert weights f32->bf16 (unchanged, verified).
// ---------------------------------------------------------------------------
__global__ __launch_bounds__(256) void convert_k(
    const float* __restrict__ gw, const float* __restrict__ pw,
    const float* __restrict__ ow, char* __restrict__ wg,
    char* __restrict__ wp, char* __restrict__ wo) {
  __shared__ float t[64][65];
  const int z = blockIdx.z;
  const int arr = z >> 3, e = z & 7;
  const float* src = (arr == 0 ? gw : arr == 1 ? pw : ow) + ((long)e << 20);
  char* dst = (arr == 0 ? wg : arr == 1 ? wp : wo) + ((long)e << 21);
  const int r0 = blockIdx.x * 64, c0 = blockIdx.y * 64;
  const int row = threadIdx.x >> 2, q = threadIdx.x & 3;
  const float4* sp = (const float4*)(src + (long)(r0 + row) * 1024 + c0 + q * 16);
  float4 v0 = sp[0], v1 = sp[1], v2 = sp[2], v3 = sp[3];
  float* tr = &t[row][q * 16];
  tr[0]=v0.x; tr[1]=v0.y; tr[2]=v0.z; tr[3]=v0.w;
  tr[4]=v1.x; tr[5]=v1.y; tr[6]=v1.z; tr[7]=v1.w;
  tr[8]=v2.x; tr[9]=v2.y; tr[10]=v2.z; tr[11]=v2.w;
  tr[12]=v3.x; tr[13]=v3.y; tr[14]=v3.z; tr[15]=v3.w;
  __syncthreads();
  const int cl = row, rq = q;
  uint4 o0, o1;
  o0.x = pk2(t[rq*16+ 0][cl], t[rq*16+ 1][cl]);
  o0.y = pk2(t[rq*16+ 2][cl], t[rq*16+ 3][cl]);
  o0.z = pk2(t[rq*16+ 4][cl], t[rq*16+ 5][cl]);
  o0.w = pk2(t[rq*16+ 6][cl], t[rq*16+ 7][cl]);
  o1.x = pk2(t[rq*16+ 8][cl], t[rq*16+ 9][cl]);
  o1.y = pk2(t[rq*16+10][cl], t[rq*16+11][cl]);
  o1.z = pk2(t[rq*16+12][cl], t[rq*16+13][cl]);
  o1.w = pk2(t[rq*16+14][cl], t[rq*16+15][cl]);
  char* dp = dst + (long)(c0 + cl) * 2048 + (long)(r0 + rq * 16) * 2;
  *(uint4*)dp = o0;
  *(uint4*)(dp + 16) = o1;
}

// ---------------------------------------------------------------------------
// Router (unchanged, verified).
// ---------------------------------------------------------------------------
__global__ __launch_bounds__(256) void router_k(
    const float* __restrict__ x, const float* __restrict__ gatew,
    float* __restrict__ logitsOut, float4* __restrict__ route,
    float* __restrict__ accum, unsigned short* __restrict__ xbo) {
  __shared__ float accB[16];
  const int tid = threadIdx.x;
  if (tid < 16) accB[tid] = 0.f;
  __syncthreads();
  const int lane = tid & 63;
  const int gwave = blockIdx.x * 4 + (tid >> 6);

  for (int g = gwave; g < 4096; g += 1024) {
    const int t0 = g * 4;
    float s[4][8];
#pragma unroll
    for (int tt = 0; tt < 4; ++tt)
#pragma unroll
      for (int e = 0; e < 8; ++e) s[tt][e] = 0.f;

    for (int i = 0; i < 16; ++i) {
      int d = lane + i * 64;
      float4 w0 = *(const float4*)(gatew + d * 8);
      float4 w1 = *(const float4*)(gatew + d * 8 + 4);
#pragma unroll
      for (int tt = 0; tt < 4; ++tt) {
        float xv = x[(long)(t0 + tt) * DDIM + d];
        if (xbo) xbo[(long)(t0 + tt) * DDIM + d] = f2bf(xv);
        s[tt][0] += xv * w0.x; s[tt][1] += xv * w0.y;
        s[tt][2] += xv * w0.z; s[tt][3] += xv * w0.w;
        s[tt][4] += xv * w1.x; s[tt][5] += xv * w1.y;
        s[tt][6] += xv * w1.z; s[tt][7] += xv * w1.w;
      }
    }
#pragma unroll
    for (int m = 1; m < 64; m <<= 1)
#pragma unroll
      for (int tt = 0; tt < 4; ++tt)
#pragma unroll
        for (int e = 0; e < 8; ++e) s[tt][e] += __shfl_xor(s[tt][e], m);

    float psum[8];
#pragma unroll
    for (int e = 0; e < 8; ++e) psum[e] = 0.f;
    int i1a[4], i2a[4];
    float w1a[4], w2a[4];
#pragma unroll
    for (int tt = 0; tt < 4; ++tt) {
      float mx = s[tt][0];
#pragma unroll
      for (int e = 1; e < 8; ++e) mx = fmaxf(mx, s[tt][e]);
      float pe[8], Z = 0.f;
#pragma unroll
      for (int e = 0; e < 8; ++e) { pe[e] = __expf(s[tt][e] - mx); Z += pe[e]; }
      float inv = 1.f / Z;
#pragma unroll
      for (int e = 0; e < 8; ++e) { pe[e] *= inv; psum[e] += pe[e]; }
      int i1 = 0; float p1 = pe[0];
#pragma unroll
      for (int e = 1; e < 8; ++e) if (pe[e] > p1) { p1 = pe[e]; i1 = e; }
      int i2 = -1; float p2 = -1.f;
#pragma unroll
      for (int e = 0; e < 8; ++e)
        if (e != i1 && pe[e] > p2) { p2 = pe[e]; i2 = e; }
      float wsum = p1 + p2;
      i1a[tt] = i1; i2a[tt] = i2;
      w1a[tt] = p1 / wsum; w2a[tt] = p2 / wsum;
    }
    if (lane < 32) {
      int tt = lane >> 3, e = lane & 7;
      logitsOut[(t0 + tt) * 8 + e] = s[tt][e];
    }
    if (lane < 32 && (lane & 7) == 0) {
      int tt = lane >> 3;
      float4 rr;
      rr.x = w1a[tt]; rr.y = w2a[tt];
      rr.z = __int_as_float(i1a[tt]); rr.w = __int_as_float(i2a[tt]);
      route[t0 + tt] = rr;
    }
    if (lane < 8) {
      float c = 0.f;
#pragma unroll
      for (int tt = 0; tt < 4; ++tt)
        c += (float)(i1a[tt] == lane) + (float)(i2a[tt] == lane);
      atomicAdd(&accB[lane], psum[lane]);
      atomicAdd(&accB[8 + lane], c);
    }
  }
  __syncthreads();
  if (tid < 16) atomicAdd(&accum[tid], accB[tid]);
}

// ---------------------------------------------------------------------------
__global__ void offsets_k(const float* __restrict__ accum,
                          int* __restrict__ offs, int* __restrict__ cursor,
                          int* __restrict__ cumT) {
  if (threadIdx.x == 0) {
    int c = 0;
#pragma unroll
    for (int e = 0; e < 8; ++e) {
      offs[e] = c; cursor[e] = c;
      c += (int)(accum[8 + e] + 0.5f);
    }
    offs[8] = c;
    int t = 0;
#pragma unroll
    for (int e = 0; e < 8; ++e) {
      cumT[e] = t;
      t += (offs[e + 1] - offs[e] + 255) >> 8;
    }
    cumT[8] = t;
  }
}

__global__ __launch_bounds__(256) void scatter_k(
    const float4* __restrict__ route, int* __restrict__ cursor,
    int* __restrict__ list, float* __restrict__ wsl) {
  int t = blockIdx.x * 256 + threadIdx.x;
  float4 rr = route[t];
  int i1 = __float_as_int(rr.z), i2 = __float_as_int(rr.w);
  int s1 = atomicAdd(&cursor[i1], 1);
  list[s1] = t; wsl[s1] = rr.x;
  int s2 = atomicAdd(&cursor[i2], 1);
  list[s2] = t; wsl[s2] = rr.y;
}

// ---------------------------------------------------------------------------
// Pass 1 grouped GEMM. Tile 256 slots x 128 h (dual g/p), 8 waves 2m x 4n.
// dbuf + counted vmcnt(8) (round-7-verified skeleton) + 4-PHASE compute:
// each phase {8 ds_read; lgkm0; 16 MFMA; s_barrier} -> LDS port and matrix
// pipe run concurrently across phase-locked waves (m201 mechanism).
// __launch_bounds__(512,2): <=256 regs, no spill (round-8 lesson).
// ---------------------------------------------------------------------------
template <int XB>
__global__ __launch_bounds__(512, 2) void pass1_k(
    const float* __restrict__ x, const unsigned short* __restrict__ xb,
    const char* __restrict__ wg, const char* __restrict__ wp,
    const int* __restrict__ list, const float* __restrict__ wsl,
    const int* __restrict__ offs, const int* __restrict__ cumT,
    char* __restrict__ hw) {
  __shared__ __align__(16) char Al[2][32768];
  __shared__ __align__(16) char Bgl[2][16384];
  __shared__ __align__(16) char Bpl[2][16384];
  const int b = blockIdx.x;
  if (b >= cumT[8]) return;
  int e = 0;
#pragma unroll
  for (int i = 1; i < 8; ++i) e += (b >= cumT[i]);
  const int tile = b - cumT[e];
  const int start = offs[e] + tile * 256;
  const int valid = min(256, offs[e + 1] - start);
  const int chunk = blockIdx.y;  // h-cols chunk*128
  const int tid = threadIdx.x, lane = tid & 63, wid = tid >> 6;

  const int l8 = lane >> 3, seg = lane & 7;
  const unsigned inrow = ((unsigned)(seg * 16)) ^ (((unsigned)l8) << 4);

  const char* asrc[4];
  unsigned adst[4];
#pragma unroll
  for (int i = 0; i < 4; ++i) {
    int row = wid * 32 + i * 8 + l8;
    int tok = list[start + min(row, valid - 1)];
    asrc[i] = (const char*)xb + ((long)tok << 11) + inrow;
    adst[i] = (unsigned)(wid * 4096 + i * 1024);
  }
  const long wbase = ((long)e << 21) + ((long)(chunk * 128) << 11);
  const char* gsrc[2];
  const char* psrc[2];
  unsigned bdst[2];
#pragma unroll
  for (int i = 0; i < 2; ++i) {
    int h = wid * 16 + i * 8 + l8;
    gsrc[i] = wg + wbase + ((long)h << 11) + inrow;
    psrc[i] = wp + wbase + ((long)h << 11) + inrow;
    bdst[i] = (unsigned)(wid * 2048 + i * 1024);
  }

  f32x4 aG[8][2], aP[8][2];
#pragma unroll
  for (int f = 0; f < 8; ++f)
#pragma unroll
    for (int j = 0; j < 2; ++j) {
      aG[f][j] = (f32x4){0.f, 0.f, 0.f, 0.f};
      aP[f][j] = (f32x4){0.f, 0.f, 0.f, 0.f};
    }

  const int col = lane & 15, kg = lane >> 4;
  const int mb = (wid >> 2) * 128, nb = (wid & 3) * 32;

#define P1_STAGE(kb, buf)                                     \
  {                                                           \
    long ko = (long)(kb) << 7;                                \
    gload16(asrc[0] + ko, &Al[buf][adst[0]]);                 \
    gload16(asrc[1] + ko, &Al[buf][adst[1]]);                 \
    gload16(asrc[2] + ko, &Al[buf][adst[2]]);                 \
    gload16(asrc[3] + ko, &Al[buf][adst[3]]);                 \
    gload16(gsrc[0] + ko, &Bgl[buf][bdst[0]]);                \
    gload16(gsrc[1] + ko, &Bgl[buf][bdst[1]]);                \
    gload16(psrc[0] + ko, &Bpl[buf][bdst[0]]);                \
    gload16(psrc[1] + ko, &Bpl[buf][bdst[1]]);                \
  }

  if (XB) {
    P1_STAGE(0, 0);
#pragma unroll 1
    for (int kb = 0; kb < 16; ++kb) {
      const int cur = kb & 1;
      if (kb < 15) {
        P1_STAGE(kb + 1, cur ^ 1);
        WAIT_VM8();  // own stage-kb loads landed; stage-kb+1 stays in flight
      } else {
        WAIT_VM0();
      }
      SBAR();  // all waves' stage-kb landed -> buf[cur] readable
#pragma unroll
      for (int ks = 0; ks < 2; ++ks) {
        bf16x8 bg[2], bp[2], af[4];
        // phase (ks, f-half 0): B frags + A 0..3
#pragma unroll
        for (int j = 0; j < 2; ++j) {
          int n = nb + j * 16 + col;
          unsigned off = (unsigned)(n * 128 + ks * 64 + kg * 16) ^
                         (((unsigned)n & 7u) << 4);
          bg[j] = *(const bf16x8*)(&Bgl[cur][0] + off);
          bp[j] = *(const bf16x8*)(&Bpl[cur][0] + off);
        }
#pragma unroll
        for (int f = 0; f < 4; ++f) {
          int r = mb + f * 16 + col;
          af[f] = *(const bf16x8*)(
              &Al[cur][0] + ((unsigned)(r * 128 + ks * 64 + kg * 16) ^
                             (((unsigned)r & 7u) << 4)));
        }
        WAIT_LGKM0();
        __builtin_amdgcn_s_setprio(1);
#pragma unroll
        for (int f = 0; f < 4; ++f)
#pragma unroll
          for (int j = 0; j < 2; ++j) {
            aG[f][j] = __builtin_amdgcn_mfma_f32_16x16x32_bf16(
                af[f], bg[j], aG[f][j], 0, 0, 0);
            aP[f][j] = __builtin_amdgcn_mfma_f32_16x16x32_bf16(
                af[f], bp[j], aP[f][j], 0, 0, 0);
          }
        __builtin_amdgcn_s_setprio(0);
        SBAR();
        // phase (ks, f-half 1): A 4..7, reuse bg/bp
#pragma unroll
        for (int f = 0; f < 4; ++f) {
          int r = mb + (f + 4) * 16 + col;
          af[f] = *(const bf16x8*)(
              &Al[cur][0] + ((unsigned)(r * 128 + ks * 64 + kg * 16) ^
                             (((unsigned)r & 7u) << 4)));
        }
        WAIT_LGKM0();
        __builtin_amdgcn_s_setprio(1);
#pragma unroll
        for (int f = 0; f < 4; ++f)
#pragma unroll
          for (int j = 0; j < 2; ++j) {
            aG[f + 4][j] = __builtin_amdgcn_mfma_f32_16x16x32_bf16(
                af[f], bg[j], aG[f + 4][j], 0, 0, 0);
            aP[f + 4][j] = __builtin_amdgcn_mfma_f32_16x16x32_bf16(
                af[f], bp[j], aP[f + 4][j], 0, 0, 0);
          }
        __builtin_amdgcn_s_setprio(0);
        SBAR();  // last phase's barrier = write-protect for next STAGE
      }
    }
  } else {
    // Fallback (ws too small for xb): 2-phase, f32 reg-staged A, single buf.
    const int sr2 = tid >> 1, q2 = tid & 1;
    const int tokS = list[start + min(sr2, valid - 1)];
    const float* axp = x + (long)tokS * DDIM + q2 * 32;
    const unsigned swzS = ((unsigned)(sr2 & 7)) << 4;
    const unsigned sbS = (unsigned)(sr2 * 128 + q2 * 64);
#pragma unroll 1
    for (int kb = 0; kb < 16; ++kb) {
      __syncthreads();
      {
        const float4* ap = (const float4*)(axp + kb * 64);
#pragma unroll
        for (int m = 0; m < 4; ++m) {
          float4 v0 = ap[m * 2], v1 = ap[m * 2 + 1];
          uint4 w;
          w.x = pk2(v0.x, v0.y); w.y = pk2(v0.z, v0.w);
          w.z = pk2(v1.x, v1.y); w.w = pk2(v1.z, v1.w);
          *(uint4*)(&Al[0][0] + ((sbS + m * 16) ^ swzS)) = w;
        }
        long ko = (long)kb << 7;
        gload16(gsrc[0] + ko, &Bgl[0][bdst[0]]);
        gload16(gsrc[1] + ko, &Bgl[0][bdst[1]]);
        gload16(psrc[0] + ko, &Bpl[0][bdst[0]]);
        gload16(psrc[1] + ko, &Bpl[0][bdst[1]]);
      }
      __syncthreads();
#pragma unroll
      for (int ks = 0; ks < 2; ++ks) {
        bf16x8 bg[2], bp[2];
#pragma unroll
        for (int j = 0; j < 2; ++j) {
          int n = nb + j * 16 + col;
          unsigned off = (unsigned)(n * 128 + ks * 64 + kg * 16) ^
                         (((unsigned)n & 7u) << 4);
          bg[j] = *(const bf16x8*)(&Bgl[0][0] + off);
          bp[j] = *(const bf16x8*)(&Bpl[0][0] + off);
        }
#pragma unroll
        for (int f = 0; f < 8; ++f) {
          int r = mb + f * 16 + col;
          bf16x8 a = *(const bf16x8*)(
              &Al[0][0] + ((unsigned)(r * 128 + ks * 64 + kg * 16) ^
                           (((unsigned)r & 7u) << 4)));
#pragma unroll
          for (int j = 0; j < 2; ++j) {
            aG[f][j] = __builtin_amdgcn_mfma_f32_16x16x32_bf16(
                a, bg[j], aG[f][j], 0, 0, 0);
            aP[f][j] = __builtin_amdgcn_mfma_f32_16x16x32_bf16(
                a, bp[j], aP[f][j], 0, 0, 0);
          }
        }
      }
    }
  }

  const int rg = lane >> 4;
#pragma unroll
  for (int f = 0; f < 8; ++f) {
#pragma unroll
    for (int r = 0; r < 4; ++r) {
      int ml = mb + f * 16 + rg * 4 + r;
      if (ml < valid) {
        int slot = start + ml;
        float wv = wsl[slot];
#pragma unroll
        for (int j = 0; j < 2; ++j) {
          float g = aG[f][j][r], p = aP[f][j][r];
          float h = g * (p / (1.f + __expf(-p))) * wv;
          int hc = chunk * 128 + nb + j * 16 + col;
          *(unsigned short*)(hw + (((long)slot << 11) + (hc << 1))) = f2bf(h);
        }
      }
    }
  }
}

// ---------------------------------------------------------------------------
// Pass 2 grouped GEMM. Tile 256 slots x 256 d, 8 waves 2m x 4n (wave 128x64).
// Same dbuf + vmcnt(8) + 4-phase schedule. atomicAdd epilogue.
// ---------------------------------------------------------------------------
__global__ __launch_bounds__(512, 2) void pass2_k(
    const char* __restrict__ hw, const char* __restrict__ wo,
    const int* __restrict__ list, const int* __restrict__ offs,
    const int* __restrict__ cumT, float* __restrict__ out) {
  __shared__ __align__(16) char Al[2][32768];
  __shared__ __align__(16) char Bl[2][32768];
  const int b = blockIdx.x;
  if (b >= cumT[8]) return;
  int e = 0;
#pragma unroll
  for (int i = 1; i < 8; ++i) e += (b >= cumT[i]);
  const int tile = b - cumT[e];
  const int start = offs[e] + tile * 256;
  const int valid = min(256, offs[e + 1] - start);
  const int chunk = blockIdx.y;  // d-cols chunk*256
  const int tid = threadIdx.x, lane = tid & 63, wid = tid >> 6;

  const int l8 = lane >> 3, seg = lane & 7;
  const unsigned inrow = ((unsigned)(seg * 16)) ^ (((unsigned)l8) << 4);

  const char* asrc[4];
  const char* bsrc[4];
  unsigned dst4[4];
#pragma unroll
  for (int i = 0; i < 4; ++i) {
    int row = wid * 32 + i * 8 + l8;
    asrc[i] = hw + ((long)(start + min(row, valid - 1)) << 11) + inrow;
    bsrc[i] = wo + ((long)e << 21) + ((long)(chunk * 256 + row) << 11) + inrow;
    dst4[i] = (unsigned)(wid * 4096 + i * 1024);
  }

  f32x4 acc[8][4];
#pragma unroll
  for (int f = 0; f < 8; ++f)
#pragma unroll
    for (int j = 0; j < 4; ++j) acc[f][j] = (f32x4){0.f, 0.f, 0.f, 0.f};

  const int col = lane & 15, kg = lane >> 4;
  const int mb = (wid >> 2) * 128, nb = (wid & 3) * 64;

#define P2_STAGE(kb, buf)                                     \
  {                                                           \
    long ko = (long)(kb) << 7;                                \
    gload16(asrc[0] + ko, &Al[buf][dst4[0]]);                 \
    gload16(asrc[1] + ko, &Al[buf][dst4[1]]);                 \
    gload16(asrc[2] + ko, &Al[buf][dst4[2]]);                 \
    gload16(asrc[3] + ko, &Al[buf][dst4[3]]);                 \
    gload16(bsrc[0] + ko, &Bl[buf][dst4[0]]);                 \
    gload16(bsrc[1] + ko, &Bl[buf][dst4[1]]);                 \
    gload16(bsrc[2] + ko, &Bl[buf][dst4[2]]);                 \
    gload16(bsrc[3] + ko, &Bl[buf][dst4[3]]);                 \
  }

  P2_STAGE(0, 0);
#pragma unroll 1
  for (int kb = 0; kb < 16; ++kb) {
    const int cur = kb & 1;
    if (kb < 15) {
      P2_STAGE(kb + 1, cur ^ 1);
      WAIT_VM8();
    } else {
      WAIT_VM0();
    }
    SBAR();
#pragma unroll
    for (int ks = 0; ks < 2; ++ks) {
      bf16x8 bf4[4], af[4];
      // phase (ks, f-half 0)
#pragma unroll
      for (int j = 0; j < 4; ++j) {
        int n = nb + j * 16 + col;
        bf4[j] = *(const bf16x8*)(
            &Bl[cur][0] + ((unsigned)(n * 128 + ks * 64 + kg * 16) ^
                           (((unsigned)n & 7u) << 4)));
      }
#pragma unroll
      for (int f = 0; f < 4; ++f) {
        int r = mb + f * 16 + col;
        af[f] = *(const bf16x8*)(
            &Al[cur][0] + ((unsigned)(r * 128 + ks * 64 + kg * 16) ^
                           (((unsigned)r & 7u) << 4)));
      }
      WAIT_LGKM0();
      __builtin_amdgcn_s_setprio(1);
#pragma unroll
      for (int f = 0; f < 4; ++f)
#pragma unroll
        for (int j = 0; j < 4; ++j)
          acc[f][j] = __builtin_amdgcn_mfma_f32_16x16x32_bf16(
              af[f], bf4[j], acc[f][j], 0, 0, 0);
      __builtin_amdgcn_s_setprio(0);
      SBAR();
      // phase (ks, f-half 1)
#pragma unroll
      for (int f = 0; f < 4; ++f) {
        int r = mb + (f + 4) * 16 + col;
        af[f] = *(const bf16x8*)(
            &Al[cur][0] + ((unsigned)(r * 128 + ks * 64 + kg * 16) ^
                           (((unsigned)r & 7u) << 4)));
      }
      WAIT_LGKM0();
      __builtin_amdgcn_s_setprio(1);
#pragma unroll
      for (int f = 0; f < 4; ++f)
#pragma unroll
        for (int j = 0; j < 4; ++j)
          acc[f + 4][j] = __builtin_amdgcn_mfma_f32_16x16x32_bf16(
              af[f], bf4[j], acc[f + 4][j], 0, 0, 0);
      __builtin_amdgcn_s_setprio(0);
      SBAR();
    }
  }

  const int rg = lane >> 4;
#pragma unroll
  for (int f = 0; f < 8; ++f) {
#pragma unroll
    for (int r = 0; r < 4; ++r) {
      int ml = mb + f * 16 + rg * 4 + r;
      if (ml < valid) {
        int token = list[start + ml];
#pragma unroll
        for (int j = 0; j < 4; ++j) {
          int c = chunk * 256 + nb + j * 16 + col;
          atomicAdd(&out[(long)token * DDIM + c], acc[f][j][r]);
        }
      }
    }
  }
}

// ---------------------------------------------------------------------------
__global__ void loss_k(const float* __restrict__ accum, float* __restrict__ out) {
  if (threadIdx.x == 0 && blockIdx.x == 0) {
    float L = 0.f;
#pragma unroll
    for (int e = 0; e < 8; ++e) L += accum[e] * accum[8 + e];
    out[0] = L * 8.f / ((float)T_TOK * (float)T_TOK);
  }
}

// ---------------------------------------------------------------------------
extern "C" void kernel_launch(void* const* d_in, const int* in_sizes, int n_in,
                              void* d_out, int out_size, void* d_ws,
                              size_t ws_size, hipStream_t stream) {
  const float* x     = (const float*)d_in[0];
  const float* gatew = (const float*)d_in[1];
  const float* gw    = (const float*)d_in[2];
  const float* pw    = (const float*)d_in[3];
  const float* ow    = (const float*)d_in[4];

  float* out       = (float*)d_out;
  float* logitsOut = out + (long)T_TOK * DDIM;
  float* lossOut   = out + (long)T_TOK * DDIM + T_TOK * 8;

  char* wsB = (char*)d_ws;
  float*  accum  = (float*)wsB;
  int*    cursor = (int*)(wsB + 64);
  int*    offs   = (int*)(wsB + 96);
  int*    cumT   = (int*)(wsB + 160);
  float4* route  = (float4*)(wsB + 1024);
  int*    list   = (int*)(wsB + 263168);
  float*  wsl    = (float*)(wsB + 394240);
  char*   wg     = wsB + (1l << 20);
  char*   wp     = wsB + 17825792;
  char*   wo     = wsB + 34603008;
  char*   hw     = wsB + 51380224;                          // 64 MiB
  unsigned short* xb = (unsigned short*)(wsB + 118489088);  // 32 MiB
  const bool big = ws_size >= 152043520ul;

  hipMemsetAsync(d_out, 0, (size_t)out_size * 4, stream);
  hipMemsetAsync(accum, 0, 64, stream);
  convert_k<<<dim3(16, 16, 24), 256, 0, stream>>>(gw, pw, ow, wg, wp, wo);
  router_k<<<256, 256, 0, stream>>>(x, gatew, logitsOut, route, accum,
                                    big ? xb : nullptr);
  offsets_k<<<1, 64, 0, stream>>>(accum, offs, cursor, cumT);
  scatter_k<<<64, 256, 0, stream>>>(route, cursor, list, wsl);
  if (big)
    pass1_k<1><<<dim3(136, 8), 512, 0, stream>>>(x, xb, wg, wp, list, wsl,
                                                 offs, cumT, hw);
  else
    pass1_k<0><<<dim3(136, 8), 512, 0, stream>>>(x, xb, wg, wp, list, wsl,
                                                 offs, cumT, hw);
  pass2_k<<<dim3(136, 4), 512, 0, stream>>>(hw, wo, list, offs, cumT, out);
  loss_k<<<1, 64, 0, stream>>>(accum, lossOut);
}

// Round 10
// 621.055 us; speedup vs baseline: 2.7572x; 1.1796x over previous
//
#include <hip/hip_runtime.h>
#include <hip/hip_bf16.h>
#include <cstdint>

// Instance: B=4,S=4096 -> T=16384, D=1024, E=8, H=1024, top_k=2. f32 in/out.
#define T_TOK 16384
#define DDIM  1024

typedef __attribute__((ext_vector_type(8))) short bf16x8;
typedef __attribute__((ext_vector_type(4))) float f32x4;

__device__ __forceinline__ unsigned short f2bf(float f) {
  unsigned u = __builtin_bit_cast(unsigned, f);
  return (unsigned short)((u + 0x7fffu + ((u >> 16) & 1u)) >> 16);  // RNE
}
__device__ __forceinline__ unsigned pk2(float a, float b) {
  return (unsigned)f2bf(a) | ((unsigned)f2bf(b) << 16);
}
__device__ __forceinline__ float bflo(unsigned u) {
  return __uint_as_float(u << 16);
}
__device__ __forceinline__ float bfhi(unsigned u) {
  return __uint_as_float(u & 0xffff0000u);
}
__device__ __forceinline__ void gload16(const void* g, void* l) {
  typedef __attribute__((address_space(1))) const unsigned int gu32;
  typedef __attribute__((address_space(3))) unsigned int lu32;
  __builtin_amdgcn_global_load_lds((gu32*)g, (lu32*)l, 16, 0, 0);
}

#define SBAR()                        \
  __builtin_amdgcn_sched_barrier(0);  \
  __builtin_amdgcn_s_barrier();       \
  __builtin_amdgcn_sched_barrier(0)
#define WAIT_VM2()                                        \
  asm volatile("s_waitcnt vmcnt(2)" ::: "memory");        \
  __builtin_amdgcn_sched_barrier(0)
#define WAIT_VM0()                                        \
  asm volatile("s_waitcnt vmcnt(0)" ::: "memory");        \
  __builtin_amdgcn_sched_barrier(0)
#define WAIT_LGKM0()                                      \
  asm volatile("s_waitcnt lgkmcnt(0)" ::: "memory");      \
  __builtin_amdgcn_sched_barrier(0)

// ---------------------------------------------------------------------------
// Transpose-convert weights f32->bf16 (unchanged, verified).
// ---------------------------------------------------------------------------
__global__ __launch_bounds__(256) void convert_k(
    const float* __restrict__ gw, const float* __restrict__ pw,
    const float* __restrict__ ow, char* __restrict__ wg,
    char* __restrict__ wp, char* __restrict__ wo) {
  __shared__ float t[64][65];
  const int z = blockIdx.z;
  const int arr = z >> 3, e = z & 7;
  const float* src = (arr == 0 ? gw : arr == 1 ? pw : ow) + ((long)e << 20);
  char* dst = (arr == 0 ? wg : arr == 1 ? wp : wo) + ((long)e << 21);
  const int r0 = blockIdx.x * 64, c0 = blockIdx.y * 64;
  const int row = threadIdx.x >> 2, q = threadIdx.x & 3;
  const float4* sp = (const float4*)(src + (long)(r0 + row) * 1024 + c0 + q * 16);
  float4 v0 = sp[0], v1 = sp[1], v2 = sp[2], v3 = sp[3];
  float* tr = &t[row][q * 16];
  tr[0]=v0.x; tr[1]=v0.y; tr[2]=v0.z; tr[3]=v0.w;
  tr[4]=v1.x; tr[5]=v1.y; tr[6]=v1.z; tr[7]=v1.w;
  tr[8]=v2.x; tr[9]=v2.y; tr[10]=v2.z; tr[11]=v2.w;
  tr[12]=v3.x; tr[13]=v3.y; tr[14]=v3.z; tr[15]=v3.w;
  __syncthreads();
  const int cl = row, rq = q;
  uint4 o0, o1;
  o0.x = pk2(t[rq*16+ 0][cl], t[rq*16+ 1][cl]);
  o0.y = pk2(t[rq*16+ 2][cl], t[rq*16+ 3][cl]);
  o0.z = pk2(t[rq*16+ 4][cl], t[rq*16+ 5][cl]);
  o0.w = pk2(t[rq*16+ 6][cl], t[rq*16+ 7][cl]);
  o1.x = pk2(t[rq*16+ 8][cl], t[rq*16+ 9][cl]);
  o1.y = pk2(t[rq*16+10][cl], t[rq*16+11][cl]);
  o1.z = pk2(t[rq*16+12][cl], t[rq*16+13][cl]);
  o1.w = pk2(t[rq*16+14][cl], t[rq*16+15][cl]);
  char* dp = dst + (long)(c0 + cl) * 2048 + (long)(r0 + rq * 16) * 2;
  *(uint4*)dp = o0;
  *(uint4*)(dp + 16) = o1;
}

// ---------------------------------------------------------------------------
// Router (unchanged, verified).
// ---------------------------------------------------------------------------
__global__ __launch_bounds__(256) void router_k(
    const float* __restrict__ x, const float* __restrict__ gatew,
    float* __restrict__ logitsOut, float4* __restrict__ route,
    float* __restrict__ accum, unsigned short* __restrict__ xbo) {
  __shared__ float accB[16];
  const int tid = threadIdx.x;
  if (tid < 16) accB[tid] = 0.f;
  __syncthreads();
  const int lane = tid & 63;
  const int gwave = blockIdx.x * 4 + (tid >> 6);

  for (int g = gwave; g < 4096; g += 1024) {
    const int t0 = g * 4;
    float s[4][8];
#pragma unroll
    for (int tt = 0; tt < 4; ++tt)
#pragma unroll
      for (int e = 0; e < 8; ++e) s[tt][e] = 0.f;

    for (int i = 0; i < 16; ++i) {
      int d = lane + i * 64;
      float4 w0 = *(const float4*)(gatew + d * 8);
      float4 w1 = *(const float4*)(gatew + d * 8 + 4);
#pragma unroll
      for (int tt = 0; tt < 4; ++tt) {
        float xv = x[(long)(t0 + tt) * DDIM + d];
        if (xbo) xbo[(long)(t0 + tt) * DDIM + d] = f2bf(xv);
        s[tt][0] += xv * w0.x; s[tt][1] += xv * w0.y;
        s[tt][2] += xv * w0.z; s[tt][3] += xv * w0.w;
        s[tt][4] += xv * w1.x; s[tt][5] += xv * w1.y;
        s[tt][6] += xv * w1.z; s[tt][7] += xv * w1.w;
      }
    }
#pragma unroll
    for (int m = 1; m < 64; m <<= 1)
#pragma unroll
      for (int tt = 0; tt < 4; ++tt)
#pragma unroll
        for (int e = 0; e < 8; ++e) s[tt][e] += __shfl_xor(s[tt][e], m);

    float psum[8];
#pragma unroll
    for (int e = 0; e < 8; ++e) psum[e] = 0.f;
    int i1a[4], i2a[4];
    float w1a[4], w2a[4];
#pragma unroll
    for (int tt = 0; tt < 4; ++tt) {
      float mx = s[tt][0];
#pragma unroll
      for (int e = 1; e < 8; ++e) mx = fmaxf(mx, s[tt][e]);
      float pe[8], Z = 0.f;
#pragma unroll
      for (int e = 0; e < 8; ++e) { pe[e] = __expf(s[tt][e] - mx); Z += pe[e]; }
      float inv = 1.f / Z;
#pragma unroll
      for (int e = 0; e < 8; ++e) { pe[e] *= inv; psum[e] += pe[e]; }
      int i1 = 0; float p1 = pe[0];
#pragma unroll
      for (int e = 1; e < 8; ++e) if (pe[e] > p1) { p1 = pe[e]; i1 = e; }
      int i2 = -1; float p2 = -1.f;
#pragma unroll
      for (int e = 0; e < 8; ++e)
        if (e != i1 && pe[e] > p2) { p2 = pe[e]; i2 = e; }
      float wsum = p1 + p2;
      i1a[tt] = i1; i2a[tt] = i2;
      w1a[tt] = p1 / wsum; w2a[tt] = p2 / wsum;
    }
    if (lane < 32) {
      int tt = lane >> 3, e = lane & 7;
      logitsOut[(t0 + tt) * 8 + e] = s[tt][e];
    }
    if (lane < 32 && (lane & 7) == 0) {
      int tt = lane >> 3;
      float4 rr;
      rr.x = w1a[tt]; rr.y = w2a[tt];
      rr.z = __int_as_float(i1a[tt]); rr.w = __int_as_float(i2a[tt]);
      route[t0 + tt] = rr;
    }
    if (lane < 8) {
      float c = 0.f;
#pragma unroll
      for (int tt = 0; tt < 4; ++tt)
        c += (float)(i1a[tt] == lane) + (float)(i2a[tt] == lane);
      atomicAdd(&accB[lane], psum[lane]);
      atomicAdd(&accB[8 + lane], c);
    }
  }
  __syncthreads();
  if (tid < 16) atomicAdd(&accum[tid], accB[tid]);
}

// ---------------------------------------------------------------------------
__global__ void offsets_k(const float* __restrict__ accum,
                          int* __restrict__ offs, int* __restrict__ cursor,
                          int* __restrict__ cumT) {
  if (threadIdx.x == 0) {
    int c = 0;
#pragma unroll
    for (int e = 0; e < 8; ++e) {
      offs[e] = c; cursor[e] = c;
      c += (int)(accum[8 + e] + 0.5f);
    }
    offs[8] = c;
    int t = 0;
#pragma unroll
    for (int e = 0; e < 8; ++e) {
      cumT[e] = t;
      t += (offs[e + 1] - offs[e] + 255) >> 8;
    }
    cumT[8] = t;
  }
}

__global__ __launch_bounds__(256) void scatter_k(
    const float4* __restrict__ route, int* __restrict__ cursor,
    int* __restrict__ list, float* __restrict__ wsl,
    int* __restrict__ slots) {
  int t = blockIdx.x * 256 + threadIdx.x;
  float4 rr = route[t];
  int i1 = __float_as_int(rr.z), i2 = __float_as_int(rr.w);
  int s1 = atomicAdd(&cursor[i1], 1);
  list[s1] = t; wsl[s1] = rr.x;
  int s2 = atomicAdd(&cursor[i2], 1);
  list[s2] = t; wsl[s2] = rr.y;
  slots[t * 2] = s1; slots[t * 2 + 1] = s2;
}

// ---------------------------------------------------------------------------
// Pass 1 grouped GEMM. Tile 256 slots x 128 h (dual g/p), 8 waves 2m x 4n.
// m201-style schedule: per K-tile boundary {SBAR; part0(kt+1); vmcnt(2);
// SBAR} then 4 phases {ds_reads; 2-load part; SBAR; lgkm0; setprio 16-MFMA}.
// Reads issued BEFORE the barrier -> latency hides under barrier skew; vmcnt
// never drains mid-loop (2 loads always in flight across the boundary wait).
// ---------------------------------------------------------------------------
template <int XB>
__global__ __launch_bounds__(512, 2) void pass1_k(
    const float* __restrict__ x, const unsigned short* __restrict__ xb,
    const char* __restrict__ wg, const char* __restrict__ wp,
    const int* __restrict__ list, const float* __restrict__ wsl,
    const int* __restrict__ offs, const int* __restrict__ cumT,
    char* __restrict__ hw) {
  __shared__ __align__(16) char Al[2][32768];
  __shared__ __align__(16) char Bgl[2][16384];
  __shared__ __align__(16) char Bpl[2][16384];
  const int b = blockIdx.x;
  if (b >= cumT[8]) return;
  int e = 0;
#pragma unroll
  for (int i = 1; i < 8; ++i) e += (b >= cumT[i]);
  const int tile = b - cumT[e];
  const int start = offs[e] + tile * 256;
  const int valid = min(256, offs[e + 1] - start);
  const int chunk = blockIdx.y;  // h-cols chunk*128
  const int tid = threadIdx.x, lane = tid & 63, wid = tid >> 6;

  const int l8 = lane >> 3, seg = lane & 7;
  const unsigned inrow = ((unsigned)(seg * 16)) ^ (((unsigned)l8) << 4);

  const char* asrc[4];
  unsigned adst[4];
#pragma unroll
  for (int i = 0; i < 4; ++i) {
    int row = wid * 32 + i * 8 + l8;
    int tok = list[start + min(row, valid - 1)];
    asrc[i] = (const char*)xb + ((long)tok << 11) + inrow;
    adst[i] = (unsigned)(wid * 4096 + i * 1024);
  }
  const long wbase = ((long)e << 21) + ((long)(chunk * 128) << 11);
  const char* gsrc[2];
  const char* psrc[2];
  unsigned bdst[2];
#pragma unroll
  for (int i = 0; i < 2; ++i) {
    int h = wid * 16 + i * 8 + l8;
    gsrc[i] = wg + wbase + ((long)h << 11) + inrow;
    psrc[i] = wp + wbase + ((long)h << 11) + inrow;
    bdst[i] = (unsigned)(wid * 2048 + i * 1024);
  }

  f32x4 aG[8][2], aP[8][2];
#pragma unroll
  for (int f = 0; f < 8; ++f)
#pragma unroll
    for (int j = 0; j < 2; ++j) {
      aG[f][j] = (f32x4){0.f, 0.f, 0.f, 0.f};
      aP[f][j] = (f32x4){0.f, 0.f, 0.f, 0.f};
    }

  const int col = lane & 15, kg = lane >> 4;
  const int mb = (wid >> 2) * 128, nb = (wid & 3) * 32;

#define P1_PART(kb, buf, part)                                \
  {                                                           \
    long ko = (long)(kb) << 7;                                \
    if ((part) == 0) {                                        \
      gload16(asrc[0] + ko, &Al[buf][adst[0]]);               \
      gload16(asrc[1] + ko, &Al[buf][adst[1]]);               \
    } else if ((part) == 1) {                                 \
      gload16(asrc[2] + ko, &Al[buf][adst[2]]);               \
      gload16(asrc[3] + ko, &Al[buf][adst[3]]);               \
    } else if ((part) == 2) {                                 \
      gload16(gsrc[0] + ko, &Bgl[buf][bdst[0]]);              \
      gload16(gsrc[1] + ko, &Bgl[buf][bdst[1]]);              \
    } else {                                                  \
      gload16(psrc[0] + ko, &Bpl[buf][bdst[0]]);              \
      gload16(psrc[1] + ko, &Bpl[buf][bdst[1]]);              \
    }                                                         \
  }

  if (XB) {
    P1_PART(0, 0, 0); P1_PART(0, 0, 1); P1_PART(0, 0, 2); P1_PART(0, 0, 3);
#pragma unroll 1
    for (int kb = 0; kb < 16; ++kb) {
      const int cur = kb & 1, nxt = cur ^ 1;
      SBAR();  // all waves passed last phase's lgkm0 -> buf[nxt] free
      if (kb < 15) {
        P1_PART(kb + 1, nxt, 0);
        WAIT_VM2();  // tile kb's 8 loads landed; 2 newer stay in flight
      } else {
        WAIT_VM0();
      }
      SBAR();  // all waves' tile-kb loads landed -> buf[cur] published
#pragma unroll
      for (int ks = 0; ks < 2; ++ks) {
        bf16x8 bg[2], bp[2], af[4];
        // phase 2*ks: B frags + A frags 0..3
#pragma unroll
        for (int j = 0; j < 2; ++j) {
          int n = nb + j * 16 + col;
          unsigned off = (unsigned)(n * 128 + ks * 64 + kg * 16) ^
                         (((unsigned)n & 7u) << 4);
          bg[j] = *(const bf16x8*)(&Bgl[cur][0] + off);
          bp[j] = *(const bf16x8*)(&Bpl[cur][0] + off);
        }
#pragma unroll
        for (int f = 0; f < 4; ++f) {
          int r = mb + f * 16 + col;
          af[f] = *(const bf16x8*)(
              &Al[cur][0] + ((unsigned)(r * 128 + ks * 64 + kg * 16) ^
                             (((unsigned)r & 7u) << 4)));
        }
        if (kb < 15 && (2 * ks) < 3) P1_PART(kb + 1, nxt, 2 * ks + 1);
        SBAR();       // reads in flight during barrier arrival skew
        WAIT_LGKM0();
        __builtin_amdgcn_s_setprio(1);
#pragma unroll
        for (int f = 0; f < 4; ++f)
#pragma unroll
          for (int j = 0; j < 2; ++j) {
            aG[f][j] = __builtin_amdgcn_mfma_f32_16x16x32_bf16(
                af[f], bg[j], aG[f][j], 0, 0, 0);
            aP[f][j] = __builtin_amdgcn_mfma_f32_16x16x32_bf16(
                af[f], bp[j], aP[f][j], 0, 0, 0);
          }
        __builtin_amdgcn_s_setprio(0);
        // phase 2*ks+1: A frags 4..7 (reuse bg,bp)
#pragma unroll
        for (int f = 0; f < 4; ++f) {
          int r = mb + (f + 4) * 16 + col;
          af[f] = *(const bf16x8*)(
              &Al[cur][0] + ((unsigned)(r * 128 + ks * 64 + kg * 16) ^
                             (((unsigned)r & 7u) << 4)));
        }
        if (kb < 15 && (2 * ks + 1) < 3) P1_PART(kb + 1, nxt, 2 * ks + 2);
        SBAR();
        WAIT_LGKM0();
        __builtin_amdgcn_s_setprio(1);
#pragma unroll
        for (int f = 0; f < 4; ++f)
#pragma unroll
          for (int j = 0; j < 2; ++j) {
            aG[f + 4][j] = __builtin_amdgcn_mfma_f32_16x16x32_bf16(
                af[f], bg[j], aG[f + 4][j], 0, 0, 0);
            aP[f + 4][j] = __builtin_amdgcn_mfma_f32_16x16x32_bf16(
                af[f], bp[j], aP[f + 4][j], 0, 0, 0);
          }
        __builtin_amdgcn_s_setprio(0);
      }
    }
  } else {
    // Fallback (ws too small for xb): 2-phase, f32 reg-staged A, single buf.
    const int sr2 = tid >> 1, q2 = tid & 1;
    const int tokS = list[start + min(sr2, valid - 1)];
    const float* axp = x + (long)tokS * DDIM + q2 * 32;
    const unsigned swzS = ((unsigned)(sr2 & 7)) << 4;
    const unsigned sbS = (unsigned)(sr2 * 128 + q2 * 64);
#pragma unroll 1
    for (int kb = 0; kb < 16; ++kb) {
      __syncthreads();
      {
        const float4* ap = (const float4*)(axp + kb * 64);
#pragma unroll
        for (int m = 0; m < 4; ++m) {
          float4 v0 = ap[m * 2], v1 = ap[m * 2 + 1];
          uint4 w;
          w.x = pk2(v0.x, v0.y); w.y = pk2(v0.z, v0.w);
          w.z = pk2(v1.x, v1.y); w.w = pk2(v1.z, v1.w);
          *(uint4*)(&Al[0][0] + ((sbS + m * 16) ^ swzS)) = w;
        }
        long ko = (long)kb << 7;
        gload16(gsrc[0] + ko, &Bgl[0][bdst[0]]);
        gload16(gsrc[1] + ko, &Bgl[0][bdst[1]]);
        gload16(psrc[0] + ko, &Bpl[0][bdst[0]]);
        gload16(psrc[1] + ko, &Bpl[0][bdst[1]]);
      }
      __syncthreads();
#pragma unroll
      for (int ks = 0; ks < 2; ++ks) {
        bf16x8 bg[2], bp[2];
#pragma unroll
        for (int j = 0; j < 2; ++j) {
          int n = nb + j * 16 + col;
          unsigned off = (unsigned)(n * 128 + ks * 64 + kg * 16) ^
                         (((unsigned)n & 7u) << 4);
          bg[j] = *(const bf16x8*)(&Bgl[0][0] + off);
          bp[j] = *(const bf16x8*)(&Bpl[0][0] + off);
        }
#pragma unroll
        for (int f = 0; f < 8; ++f) {
          int r = mb + f * 16 + col;
          bf16x8 a = *(const bf16x8*)(
              &Al[0][0] + ((unsigned)(r * 128 + ks * 64 + kg * 16) ^
                           (((unsigned)r & 7u) << 4)));
#pragma unroll
          for (int j = 0; j < 2; ++j) {
            aG[f][j] = __builtin_amdgcn_mfma_f32_16x16x32_bf16(
                a, bg[j], aG[f][j], 0, 0, 0);
            aP[f][j] = __builtin_amdgcn_mfma_f32_16x16x32_bf16(
                a, bp[j], aP[f][j], 0, 0, 0);
          }
        }
      }
    }
  }

  const int rg = lane >> 4;
#pragma unroll
  for (int f = 0; f < 8; ++f) {
#pragma unroll
    for (int r = 0; r < 4; ++r) {
      int ml = mb + f * 16 + rg * 4 + r;
      if (ml < valid) {
        int slot = start + ml;
        float wv = wsl[slot];
#pragma unroll
        for (int j = 0; j < 2; ++j) {
          float g = aG[f][j][r], p = aP[f][j][r];
          float h = g * (p / (1.f + __expf(-p))) * wv;
          int hc = chunk * 128 + nb + j * 16 + col;
          *(unsigned short*)(hw + (((long)slot << 11) + (hc << 1))) = f2bf(h);
        }
      }
    }
  }
}

// ---------------------------------------------------------------------------
// Pass 2 grouped GEMM. Tile 256 slots x 256 d, 8 waves 2m x 4n (wave 128x64).
// Same m201-style schedule. Epilogue: ATOMIC=1 -> atomicAdd into zeroed out;
// ATOMIC=0 -> bf16 rows into hw2 (combined later; no atomics, no memset).
// ---------------------------------------------------------------------------
template <int ATOMIC>
__global__ __launch_bounds__(512, 2) void pass2_k(
    const char* __restrict__ hw, const char* __restrict__ wo,
    const int* __restrict__ list, const int* __restrict__ offs,
    const int* __restrict__ cumT, float* __restrict__ out,
    unsigned short* __restrict__ hw2) {
  __shared__ __align__(16) char Al[2][32768];
  __shared__ __align__(16) char Bl[2][32768];
  const int b = blockIdx.x;
  if (b >= cumT[8]) return;
  int e = 0;
#pragma unroll
  for (int i = 1; i < 8; ++i) e += (b >= cumT[i]);
  const int tile = b - cumT[e];
  const int start = offs[e] + tile * 256;
  const int valid = min(256, offs[e + 1] - start);
  const int chunk = blockIdx.y;  // d-cols chunk*256
  const int tid = threadIdx.x, lane = tid & 63, wid = tid >> 6;

  const int l8 = lane >> 3, seg = lane & 7;
  const unsigned inrow = ((unsigned)(seg * 16)) ^ (((unsigned)l8) << 4);

  const char* asrc[4];
  const char* bsrc[4];
  unsigned dst4[4];
#pragma unroll
  for (int i = 0; i < 4; ++i) {
    int row = wid * 32 + i * 8 + l8;
    asrc[i] = hw + ((long)(start + min(row, valid - 1)) << 11) + inrow;
    bsrc[i] = wo + ((long)e << 21) + ((long)(chunk * 256 + row) << 11) + inrow;
    dst4[i] = (unsigned)(wid * 4096 + i * 1024);
  }

  f32x4 acc[8][4];
#pragma unroll
  for (int f = 0; f < 8; ++f)
#pragma unroll
    for (int j = 0; j < 4; ++j) acc[f][j] = (f32x4){0.f, 0.f, 0.f, 0.f};

  const int col = lane & 15, kg = lane >> 4;
  const int mb = (wid >> 2) * 128, nb = (wid & 3) * 64;

#define P2_PART(kb, buf, part)                                \
  {                                                           \
    long ko = (long)(kb) << 7;                                \
    if ((part) == 0) {                                        \
      gload16(asrc[0] + ko, &Al[buf][dst4[0]]);               \
      gload16(asrc[1] + ko, &Al[buf][dst4[1]]);               \
    } else if ((part) == 1) {                                 \
      gload16(asrc[2] + ko, &Al[buf][dst4[2]]);               \
      gload16(asrc[3] + ko, &Al[buf][dst4[3]]);               \
    } else if ((part) == 2) {                                 \
      gload16(bsrc[0] + ko, &Bl[buf][dst4[0]]);               \
      gload16(bsrc[1] + ko, &Bl[buf][dst4[1]]);               \
    } else {                                                  \
      gload16(bsrc[2] + ko, &Bl[buf][dst4[2]]);               \
      gload16(bsrc[3] + ko, &Bl[buf][dst4[3]]);               \
    }                                                         \
  }

  P2_PART(0, 0, 0); P2_PART(0, 0, 1); P2_PART(0, 0, 2); P2_PART(0, 0, 3);
#pragma unroll 1
  for (int kb = 0; kb < 16; ++kb) {
    const int cur = kb & 1, nxt = cur ^ 1;
    SBAR();
    if (kb < 15) {
      P2_PART(kb + 1, nxt, 0);
      WAIT_VM2();
    } else {
      WAIT_VM0();
    }
    SBAR();
#pragma unroll
    for (int ks = 0; ks < 2; ++ks) {
      bf16x8 bf4[4], af[4];
      // phase 2*ks: B frags + A frags 0..3
#pragma unroll
      for (int j = 0; j < 4; ++j) {
        int n = nb + j * 16 + col;
        bf4[j] = *(const bf16x8*)(
            &Bl[cur][0] + ((unsigned)(n * 128 + ks * 64 + kg * 16) ^
                           (((unsigned)n & 7u) << 4)));
      }
#pragma unroll
      for (int f = 0; f < 4; ++f) {
        int r = mb + f * 16 + col;
        af[f] = *(const bf16x8*)(
            &Al[cur][0] + ((unsigned)(r * 128 + ks * 64 + kg * 16) ^
                           (((unsigned)r & 7u) << 4)));
      }
      if (kb < 15 && (2 * ks) < 3) P2_PART(kb + 1, nxt, 2 * ks + 1);
      SBAR();
      WAIT_LGKM0();
      __builtin_amdgcn_s_setprio(1);
#pragma unroll
      for (int f = 0; f < 4; ++f)
#pragma unroll
        for (int j = 0; j < 4; ++j)
          acc[f][j] = __builtin_amdgcn_mfma_f32_16x16x32_bf16(
              af[f], bf4[j], acc[f][j], 0, 0, 0);
      __builtin_amdgcn_s_setprio(0);
      // phase 2*ks+1: A frags 4..7
#pragma unroll
      for (int f = 0; f < 4; ++f) {
        int r = mb + (f + 4) * 16 + col;
        af[f] = *(const bf16x8*)(
            &Al[cur][0] + ((unsigned)(r * 128 + ks * 64 + kg * 16) ^
                           (((unsigned)r & 7u) << 4)));
      }
      if (kb < 15 && (2 * ks + 1) < 3) P2_PART(kb + 1, nxt, 2 * ks + 2);
      SBAR();
      WAIT_LGKM0();
      __builtin_amdgcn_s_setprio(1);
#pragma unroll
      for (int f = 0; f < 4; ++f)
#pragma unroll
        for (int j = 0; j < 4; ++j)
          acc[f + 4][j] = __builtin_amdgcn_mfma_f32_16x16x32_bf16(
              af[f], bf4[j], acc[f + 4][j], 0, 0, 0);
      __builtin_amdgcn_s_setprio(0);
    }
  }

  const int rg = lane >> 4;
#pragma unroll
  for (int f = 0; f < 8; ++f) {
#pragma unroll
    for (int r = 0; r < 4; ++r) {
      int ml = mb + f * 16 + rg * 4 + r;
      if (ml < valid) {
        int slot = start + ml;
#pragma unroll
        for (int j = 0; j < 4; ++j) {
          int c = chunk * 256 + nb + j * 16 + col;
          if (ATOMIC) {
            atomicAdd(&out[(long)list[slot] * DDIM + c], acc[f][j][r]);
          } else {
            hw2[((long)slot << 10) + c] = f2bf(acc[f][j][r]);
          }
        }
      }
    }
  }
}

// ---------------------------------------------------------------------------
// Combine: out[t] = hw2[slot1(t)] + hw2[slot2(t)]. 128 thr = one 2KB row.
// ---------------------------------------------------------------------------
__global__ __launch_bounds__(128) void combine_k(
    const unsigned short* __restrict__ hw2, const int* __restrict__ slots,
    float* __restrict__ out) {
  const int t = blockIdx.x;
  const int s1 = slots[t * 2], s2 = slots[t * 2 + 1];
  const int c = threadIdx.x;  // 8 cols each
  uint4 a = *(const uint4*)(hw2 + ((long)s1 << 10) + c * 8);
  uint4 b = *(const uint4*)(hw2 + ((long)s2 << 10) + c * 8);
  float4 o0, o1;
  o0.x = bflo(a.x) + bflo(b.x); o0.y = bfhi(a.x) + bfhi(b.x);
  o0.z = bflo(a.y) + bflo(b.y); o0.w = bfhi(a.y) + bfhi(b.y);
  o1.x = bflo(a.z) + bflo(b.z); o1.y = bfhi(a.z) + bfhi(b.z);
  o1.z = bflo(a.w) + bflo(b.w); o1.w = bfhi(a.w) + bfhi(b.w);
  float* op = out + (long)t * DDIM + c * 8;
  *(float4*)op = o0;
  *(float4*)(op + 4) = o1;
}

// ---------------------------------------------------------------------------
__global__ void loss_k(const float* __restrict__ accum, float* __restrict__ out) {
  if (threadIdx.x == 0 && blockIdx.x == 0) {
    float L = 0.f;
#pragma unroll
    for (int e = 0; e < 8; ++e) L += accum[e] * accum[8 + e];
    out[0] = L * 8.f / ((float)T_TOK * (float)T_TOK);
  }
}

// ---------------------------------------------------------------------------
extern "C" void kernel_launch(void* const* d_in, const int* in_sizes, int n_in,
                              void* d_out, int out_size, void* d_ws,
                              size_t ws_size, hipStream_t stream) {
  const float* x     = (const float*)d_in[0];
  const float* gatew = (const float*)d_in[1];
  const float* gw    = (const float*)d_in[2];
  const float* pw    = (const float*)d_in[3];
  const float* ow    = (const float*)d_in[4];

  float* out       = (float*)d_out;
  float* logitsOut = out + (long)T_TOK * DDIM;
  float* lossOut   = out + (long)T_TOK * DDIM + T_TOK * 8;

  char* wsB = (char*)d_ws;
  float*  accum  = (float*)wsB;
  int*    cursor = (int*)(wsB + 64);
  int*    offs   = (int*)(wsB + 96);
  int*    cumT   = (int*)(wsB + 160);
  float4* route  = (float4*)(wsB + 1024);
  int*    list   = (int*)(wsB + 263168);
  float*  wsl    = (float*)(wsB + 394240);
  int*    slots  = (int*)(wsB + 525312);    // 128 KiB, ends 656384 < 1 MiB
  char*   wg     = wsB + (1l << 20);
  char*   wp     = wsB + 17825792;
  char*   wo     = wsB + 34603008;
  char*   hw     = wsB + 51380224;                          // 64 MiB
  unsigned short* xb  = (unsigned short*)(wsB + 118489088); // 32 MiB
  unsigned short* hw2 = (unsigned short*)(wsB + 152043520); // 64 MiB
  const bool big  = ws_size >= 152043520ul;
  const bool comb = ws_size >= 219152384ul;

  if (!comb) hipMemsetAsync(d_out, 0, (size_t)out_size * 4, stream);
  hipMemsetAsync(accum, 0, 64, stream);
  convert_k<<<dim3(16, 16, 24), 256, 0, stream>>>(gw, pw, ow, wg, wp, wo);
  router_k<<<256, 256, 0, stream>>>(x, gatew, logitsOut, route, accum,
                                    big ? xb : nullptr);
  offsets_k<<<1, 64, 0, stream>>>(accum, offs, cursor, cumT);
  scatter_k<<<64, 256, 0, stream>>>(route, cursor, list, wsl, slots);
  if (big)
    pass1_k<1><<<dim3(136, 8), 512, 0, stream>>>(x, xb, wg, wp, list, wsl,
                                                 offs, cumT, hw);
  else
    pass1_k<0><<<dim3(136, 8), 512, 0, stream>>>(x, xb, wg, wp, list, wsl,
                                                 offs, cumT, hw);
  if (comb) {
    pass2_k<0><<<dim3(136, 4), 512, 0, stream>>>(hw, wo, list, offs, cumT,
                                                 out, hw2);
    combine_k<<<T_TOK, 128, 0, stream>>>(hw2, slots, out);
  } else {
    pass2_k<1><<<dim3(136, 4), 512, 0, stream>>>(hw, wo, list, offs, cumT,
                                                 out, hw2);
  }
  loss_k<<<1, 64, 0, stream>>>(accum, lossOut);
}